// Round 13
// baseline (213.331 us; speedup 1.0000x reference)
//
#include <hip/hip_runtime.h>
#include <math.h>

#define B_ 4
#define S_ 1024
#define E_ 1024
#define H_ 16
#define HD_ 64

typedef float4 f4;
typedef __bf16 bf16x8 __attribute__((ext_vector_type(8)));
typedef _Float16 f16x8 __attribute__((ext_vector_type(8)));
typedef ushort u16x8 __attribute__((ext_vector_type(8)));
typedef float f32x4 __attribute__((ext_vector_type(4)));

// async global->LDS, 16B per lane. LDS dest = wave-uniform base + lane*16.
__device__ __forceinline__ void gl16(const void* g, void* l) {
  __builtin_amdgcn_global_load_lds(
      (__attribute__((address_space(1))) void*)g,
      (__attribute__((address_space(3))) void*)l, 16, 0, 0);
}

template <int MT> __device__ __forceinline__ ushort cvt_hi(float x) {
  if constexpr (MT == 0) return __builtin_bit_cast(ushort, (__bf16)x);
  else return __builtin_bit_cast(ushort, (_Float16)x);
}
template <int MT> __device__ __forceinline__ float cvt_back(ushort h) {
  if constexpr (MT == 0) {
    union { unsigned u; float f; } v; v.u = (unsigned)h << 16; return v.f;
  } else {
    return (float)__builtin_bit_cast(_Float16, h);
  }
}
template <int MT> __device__ __forceinline__ f32x4 mfma_t(u16x8 a, u16x8 b, f32x4 c) {
  if constexpr (MT == 0)
    return __builtin_amdgcn_mfma_f32_16x16x32_bf16(
        __builtin_bit_cast(bf16x8, a), __builtin_bit_cast(bf16x8, b), c, 0, 0, 0);
  else
    return __builtin_amdgcn_mfma_f32_16x16x32_f16(
        __builtin_bit_cast(f16x8, a), __builtin_bit_cast(f16x8, b), c, 0, 0, 0);
}
// frag load, full-row layout: row stride 64 ushorts, chunk XOR row&7 (8 slots).
__device__ __forceinline__ u16x8 ldfrag(const ushort* s, int row, int chunk) {
  return *reinterpret_cast<const u16x8*>(s + row * 64 + ((chunk ^ (row & 7)) << 3));
}
// frag load, pair-packed layout: line = 2 rows x 32 k in 64 ushorts; position
// ((row&1)<<2|chunk) XOR line&7 -> 8 slots -> 2-way bank aliasing (free, m136).
__device__ __forceinline__ u16x8 ldfragP(const ushort* s, int row, int chunk) {
  const int L = row >> 1;
  const int p = ((((row & 1) << 2) | chunk) ^ (L & 7)) << 3;
  return *reinterpret_cast<const u16x8*>(s + L * 64 + p);
}

// ws16 layout (units of MSZ = 1M ushorts = 2 MB):
// 0:Wqf  1:Wkh 2:Wkl  3:Wvf 4:Wof  5..8:xf  9..12:xbh 13..16:xbl
// 17..20:qh  21..24:kh 25..28:kl  29..32:vt  33..36:aoh

// ---------------------------------------------------------------------------
// prep_x: x fp32 -> fp16 (Q/V path) + bf16 hi/lo (K path, denorm-safe splits)
// ---------------------------------------------------------------------------
__global__ __launch_bounds__(256) void prep_x(
    const float* __restrict__ x, ushort* __restrict__ xf,
    ushort* __restrict__ xbh, ushort* __restrict__ xbl)
{
  const size_t i = ((size_t)blockIdx.x * 256 + threadIdx.x) * 8;
  float v[8];
  *reinterpret_cast<f4*>(v)     = *reinterpret_cast<const f4*>(x + i);
  *reinterpret_cast<f4*>(v + 4) = *reinterpret_cast<const f4*>(x + i + 4);
  unsigned fw[4], hw[4], lw[4];
#pragma unroll
  for (int p = 0; p < 4; ++p) {
    const float a = v[2 * p], b = v[2 * p + 1];
    fw[p] = (unsigned)cvt_hi<1>(a) | ((unsigned)cvt_hi<1>(b) << 16);
    const ushort ha = cvt_hi<0>(a), hb = cvt_hi<0>(b);
    hw[p] = (unsigned)ha | ((unsigned)hb << 16);
    lw[p] = (unsigned)cvt_hi<0>(a - cvt_back<0>(ha)) |
            ((unsigned)cvt_hi<0>(b - cvt_back<0>(hb)) << 16);
  }
  *reinterpret_cast<uint4*>(xf + i)  = make_uint4(fw[0], fw[1], fw[2], fw[3]);
  *reinterpret_cast<uint4*>(xbh + i) = make_uint4(hw[0], hw[1], hw[2], hw[3]);
  *reinterpret_cast<uint4*>(xbl + i) = make_uint4(lw[0], lw[1], lw[2], lw[3]);
}

// ---------------------------------------------------------------------------
// prep_w: W fp32 [k][n] -> transposed Wt[n][k]: Wq/Wv/Wo fp16; Wk bf16 hi/lo.
// ---------------------------------------------------------------------------
__global__ __launch_bounds__(256) void prep_w(
    const float* __restrict__ Wq, const float* __restrict__ Wk,
    const float* __restrict__ Wv, const float* __restrict__ Wo,
    ushort* __restrict__ ws16)
{
  const int MSZ = 1024 * 1024;
  const int mat = blockIdx.z;
  const int n0 = blockIdx.x * 64, k0 = blockIdx.y * 64;
  const float* W = mat == 0 ? Wq : mat == 1 ? Wk : mat == 2 ? Wv : Wo;
  ushort* Oh = ws16 + (mat == 0 ? 0 : mat == 1 ? 1 : mat == 2 ? 3 : 4) * MSZ;
  ushort* Ol = mat == 1 ? ws16 + 2 * MSZ : nullptr;

  __shared__ __align__(16) float tile[64][65];
  const int t = threadIdx.x;
  const int r = t >> 2, cq = t & 3;
#pragma unroll
  for (int j = 0; j < 4; ++j) {
    const f4 v = *reinterpret_cast<const f4*>(&W[(size_t)(k0 + r) * 1024 + n0 + cq * 16 + 4 * j]);
    tile[r][cq * 16 + 4 * j + 0] = v.x;
    tile[r][cq * 16 + 4 * j + 1] = v.y;
    tile[r][cq * 16 + 4 * j + 2] = v.z;
    tile[r][cq * 16 + 4 * j + 3] = v.w;
  }
  __syncthreads();
  unsigned hw[8], lw[8];
#pragma unroll
  for (int p = 0; p < 8; ++p) {
    const float a = tile[cq * 16 + 2 * p][r];
    const float b = tile[cq * 16 + 2 * p + 1][r];
    if (mat == 1) {
      const ushort ha = cvt_hi<0>(a), hb = cvt_hi<0>(b);
      hw[p] = (unsigned)ha | ((unsigned)hb << 16);
      lw[p] = (unsigned)cvt_hi<0>(a - cvt_back<0>(ha)) |
              ((unsigned)cvt_hi<0>(b - cvt_back<0>(hb)) << 16);
    } else {
      hw[p] = (unsigned)cvt_hi<1>(a) | ((unsigned)cvt_hi<1>(b) << 16);
    }
  }
  ushort* dh = Oh + (size_t)(n0 + r) * 1024 + k0 + cq * 16;
  *reinterpret_cast<uint4*>(dh)     = make_uint4(hw[0], hw[1], hw[2], hw[3]);
  *reinterpret_cast<uint4*>(dh + 8) = make_uint4(hw[4], hw[5], hw[6], hw[7]);
  if (Ol) {
    ushort* dl = Ol + (size_t)(n0 + r) * 1024 + k0 + cq * 16;
    *reinterpret_cast<uint4*>(dl)     = make_uint4(lw[0], lw[1], lw[2], lw[3]);
    *reinterpret_cast<uint4*>(dl + 8) = make_uint4(lw[4], lw[5], lw[6], lw[7]);
  }
}

// ---------------------------------------------------------------------------
// MFMA GEMM, BK=32, counted-vmcnt double-buffer (R12 scheme), pair-packed LDS.
// Same LDS totals as R6 single-buffer -> same occupancy + pipelining.
// MFMA accumulation order identical to BK=64 version -> bit-identical output.
// ---------------------------------------------------------------------------
template <int TERMS, int MT, int OMODE>
__global__ __launch_bounds__(256) void gemm_mfma(
    const ushort* __restrict__ Ab, const ushort* __restrict__ Abl,
    const ushort* __restrict__ Bhg, const ushort* __restrict__ Blg,
    const float* __restrict__ bias, float scale,
    ushort* __restrict__ Oh, ushort* __restrict__ Ol, float* __restrict__ Of)
{
  const int n0 = blockIdx.x * 128;
  const int m0 = blockIdx.y * 64;
  const int t = threadIdx.x;
  const int wv = t >> 6, lane = t & 63;
  const int lr = lane & 15, lg = lane >> 4;
  const int wm = (wv >> 1) * 32, wn = (wv & 1) * 64;
  const int lsub = lane >> 3, c8 = lane & 7;

  __shared__ __align__(16) ushort Ah_s[2][2048];
  __shared__ __align__(16) ushort Al_s[TERMS == 3 ? 2 : 1][TERMS == 3 ? 2048 : 16];
  __shared__ __align__(16) ushort Bh_s[2][4096];
  __shared__ __align__(16) ushort Bl_s[TERMS == 3 ? 2 : 1][TERMS == 3 ? 4096 : 16];
  __shared__ __align__(16) ushort tr_s[OMODE == 2 ? 128 * 72 : 16];

  f32x4 acc[2][4];
#pragma unroll
  for (int mi = 0; mi < 2; ++mi)
#pragma unroll
    for (int ni = 0; ni < 4; ++ni) { f32x4 z = {0.f, 0.f, 0.f, 0.f}; acc[mi][ni] = z; }

  // pair-packed stage: line L holds rows {2L, 2L+1} x 32 k; pos p holds chunk
  // c = p ^ (L&7); c>>2 selects the row half, c&3 the k-quad.
  auto stage = [&](int kt, int cb) {
    const int k0 = kt * 32;
#pragma unroll
    for (int j = 0; j < 2; ++j) {  // B: 64 lines
      const int L = wv * 16 + j * 8 + lsub;
      const int c = c8 ^ (L & 7);
      const size_t go = (size_t)(n0 + 2 * L + (c >> 2)) * 1024 + k0 + (c & 3) * 8;
      gl16(Bhg + go, &Bh_s[cb][(wv * 16 + j * 8) * 64]);
      if constexpr (TERMS == 3) gl16(Blg + go, &Bl_s[cb][(wv * 16 + j * 8) * 64]);
    }
    {  // A: 32 lines
      const int L = wv * 8 + lsub;
      const int c = c8 ^ (L & 7);
      const size_t go = (size_t)(m0 + 2 * L + (c >> 2)) * 1024 + k0 + (c & 3) * 8;
      gl16(Ab + go, &Ah_s[cb][wv * 512]);
      if constexpr (TERMS == 3) gl16(Abl + go, &Al_s[cb][wv * 512]);
    }
  };

  stage(0, 0);
  for (int kt = 0; kt < 32; ++kt) {
    if (kt < 31) {
      stage(kt + 1, (kt + 1) & 1);
      if constexpr (TERMS == 1) asm volatile("s_waitcnt vmcnt(3)" ::: "memory");
      else                      asm volatile("s_waitcnt vmcnt(6)" ::: "memory");
    } else {
      asm volatile("s_waitcnt vmcnt(0)" ::: "memory");
    }
    __builtin_amdgcn_sched_barrier(0);
    __builtin_amdgcn_s_barrier();   // tile kt visible to all waves
    __builtin_amdgcn_sched_barrier(0);

    const int cb = kt & 1;
    const u16x8 ah0 = ldfragP(Ah_s[cb], wm + lr, lg);
    const u16x8 ah1 = ldfragP(Ah_s[cb], wm + 16 + lr, lg);
    u16x8 al0, al1;
    if constexpr (TERMS == 3) {
      al0 = ldfragP(Al_s[cb], wm + lr, lg);
      al1 = ldfragP(Al_s[cb], wm + 16 + lr, lg);
    }
#pragma unroll
    for (int ni = 0; ni < 4; ++ni) {
      const u16x8 bh = ldfragP(Bh_s[cb], wn + ni * 16 + lr, lg);
      acc[0][ni] = mfma_t<MT>(ah0, bh, acc[0][ni]);
      acc[1][ni] = mfma_t<MT>(ah1, bh, acc[1][ni]);
      if constexpr (TERMS == 3) {
        const u16x8 bl = ldfragP(Bl_s[cb], wn + ni * 16 + lr, lg);
        acc[0][ni] = mfma_t<MT>(ah0, bl, acc[0][ni]);
        acc[1][ni] = mfma_t<MT>(ah1, bl, acc[1][ni]);
        acc[0][ni] = mfma_t<MT>(al0, bh, acc[0][ni]);
        acc[1][ni] = mfma_t<MT>(al1, bh, acc[1][ni]);
      }
    }
    __builtin_amdgcn_s_barrier();   // reads done before next-iter overwrite
    __builtin_amdgcn_sched_barrier(0);
  }

  // ---- epilogue ----
  if constexpr (OMODE == 2) {
    __syncthreads();
#pragma unroll
    for (int mi = 0; mi < 2; ++mi)
#pragma unroll
      for (int ni = 0; ni < 4; ++ni)
#pragma unroll
        for (int r = 0; r < 4; ++r) {
          const int n_l = wn + ni * 16 + lr, m_l = wm + mi * 16 + lg * 4 + r;
          tr_s[n_l * 72 + m_l] = cvt_hi<1>(acc[mi][ni][r] + bias[n0 + n_l]);
        }
    __syncthreads();
    const int row = t >> 1, hf = t & 1;
    const int n_g = n0 + row;
    const int h_ = n_g >> 6, hd = n_g & 63;
    const int b_g = m0 >> 10;
    ushort* dst = Oh + ((size_t)(b_g * 16 + h_) * 64 + hd) * 1024 + (m0 & 1023) + hf * 32;
#pragma unroll
    for (int j = 0; j < 4; ++j)
      *reinterpret_cast<uint4*>(dst + 8 * j) =
          *reinterpret_cast<const uint4*>(&tr_s[row * 72 + hf * 32 + 8 * j]);
  } else {
#pragma unroll
    for (int mi = 0; mi < 2; ++mi)
#pragma unroll
      for (int ni = 0; ni < 4; ++ni) {
        const int n = n0 + wn + ni * 16 + lr;
        const float bi = bias[n];
#pragma unroll
        for (int r = 0; r < 4; ++r) {
          const int m = m0 + wm + mi * 16 + lg * 4 + r;
          const float v = (acc[mi][ni][r] + bi) * scale;
          if constexpr (OMODE == 0) {
            Of[(size_t)m * 1024 + n] = v;
          } else {
            const size_t addr =
                ((size_t)((m >> 10) * 16 + (n >> 6)) * 1024 + (m & 1023)) * 64 + (n & 63);
            if constexpr (OMODE == 1) {
              const _Float16 hv = (_Float16)v;
              Oh[addr] = __builtin_bit_cast(ushort, hv);
              Ol[addr] = cvt_hi<1>(v - (float)hv);
            } else {  // OMODE == 3
              Oh[addr] = cvt_hi<1>(v);
            }
          }
        }
      }
  }
}

// ---------------------------------------------------------------------------
// MFMA dual-softmax attention: counted-vmcnt, KVBLK=32, 5 blocks/CU (R12),
// with pass-1 depth-3 prefetch over a 6-buffer rotation (1 barrier/iter) and
// pair-packed vt tiles (2-way instead of 4-way LDS aliasing).
// Values fed to MFMA/exp identical to R12 -> bit-identical output.
// ---------------------------------------------------------------------------
__global__ __launch_bounds__(256) void attn_mfma(
    const ushort* __restrict__ qh_g, const ushort* __restrict__ kh_g,
    const ushort* __restrict__ kl_g, const ushort* __restrict__ vt_g,
    const float* __restrict__ ge, float* __restrict__ attn,
    ushort* __restrict__ aoh)
{
  __shared__ __align__(16) ushort stage_s[6][2048];  // pass1: 6-rot K-hi; pass2: 2x{kh,kl,vt}
  __shared__ __align__(16) ushort w_s[4][1024];

  const int bid = blockIdx.x;
  const int wg = (bid & 7) * 128 + (bid >> 3);  // bijective XCD swizzle (1024 = 8*128)
  const int bh = wg >> 4, qb = wg & 15;
  const int b = bh >> 4, h = bh & 15;

  const int t = threadIdx.x;
  const int wv = t >> 6, lane = t & 63;
  const int lr = lane & 15, lg = lane >> 4;
  const int q0 = qb * 64 + wv * 16;

  // Q (fp16, pre-scaled 0.125) + G (fp32 kept for u; fp16-hi for pass 1)
  u16x8 qh[2], gh[2];
  float gf[2][8];
#pragma unroll
  for (int ks = 0; ks < 2; ++ks) {
    const size_t qoff = ((size_t)bh * S_ + q0 + lr) * HD_ + ks * 32 + lg * 8;
    qh[ks] = *reinterpret_cast<const u16x8*>(qh_g + qoff);
    const float* grow = ge + ((size_t)b * S_ + q0 + lr) * HD_ + ks * 32 + lg * 8;
    *reinterpret_cast<f4*>(&gf[ks][0]) = *reinterpret_cast<const f4*>(grow);
    *reinterpret_cast<f4*>(&gf[ks][4]) = *reinterpret_cast<const f4*>(grow + 4);
#pragma unroll
    for (int e = 0; e < 8; ++e) gh[ks][e] = cvt_hi<1>(gf[ks][e]);
  }

  const ushort* khb = kh_g + (size_t)bh * S_ * HD_;
  const ushort* klb = kl_g + (size_t)bh * S_ * HD_;
  const ushort* vtb = vt_g + (size_t)bh * HD_ * S_;

  // K staging (32 keys x 64 d, full-row layout, conflict-free)
  const int krow = wv * 8 + (lane >> 3);
  const int ksw  = ((lane & 7) ^ (krow & 7)) << 3;
  auto stage_kh = [&](int kt, int bf) {
    gl16(khb + kt * 2048 + krow * 64 + ksw, &stage_s[bf][wv * 512]);
  };
  auto stage_kl = [&](int kt, int bf) {
    gl16(klb + kt * 2048 + krow * 64 + ksw, &stage_s[bf][wv * 512]);
  };
  // V staging (64 d x 32 k, pair-packed)
  const int vL = wv * 8 + (lane >> 3);
  const int vc = (lane & 7) ^ (vL & 7);
  auto stage_vt = [&](int kt, int bf) {
    gl16(vtb + kt * 32 + (size_t)(2 * vL + (vc >> 2)) * 1024 + (vc & 3) * 8,
         &stage_s[bf][wv * 512]);
  };

  float z1L[4] = {0.f, 0.f, 0.f, 0.f}, z2L[4] = {0.f, 0.f, 0.f, 0.f};

  // drain Q/G loads so vmcnt bookkeeping below is exact
  asm volatile("s_waitcnt vmcnt(0)" ::: "memory");
  __builtin_amdgcn_sched_barrier(0);

  // ---------------- pass 1: z-sums, depth-3 prefetch, 1 barrier/iter --------
  stage_kh(0, 0);
  stage_kh(1, 1);
  stage_kh(2, 2);
  {
    int bc = 0, bn = 3;
    for (int kt = 0; kt < 32; ++kt) {
      if (kt < 29) {
        stage_kh(kt + 3, bn);
        asm volatile("s_waitcnt vmcnt(3)" ::: "memory");
      } else if (kt == 29) {
        asm volatile("s_waitcnt vmcnt(2)" ::: "memory");
      } else if (kt == 30) {
        asm volatile("s_waitcnt vmcnt(1)" ::: "memory");
      } else {
        asm volatile("s_waitcnt vmcnt(0)" ::: "memory");
      }
      __builtin_amdgcn_sched_barrier(0);
      __builtin_amdgcn_s_barrier();   // tile kt visible; overwrite trails by 3
      __builtin_amdgcn_sched_barrier(0);

      const ushort* kp = stage_s[bc];
      f32x4 s1[2], s2[2];
#pragma unroll
      for (int ct = 0; ct < 2; ++ct) {
        f32x4 z = {0.f, 0.f, 0.f, 0.f};
        s1[ct] = z; s2[ct] = z;
#pragma unroll
        for (int ks = 0; ks < 2; ++ks) {
          const u16x8 khf = ldfrag(kp, ct * 16 + lr, ks * 4 + lg);
          s1[ct] = mfma_t<1>(qh[ks], khf, s1[ct]);
          s2[ct] = mfma_t<1>(gh[ks], khf, s2[ct]);
        }
      }
#pragma unroll
      for (int r = 0; r < 4; ++r)
#pragma unroll
        for (int ct = 0; ct < 2; ++ct) {
          z1L[r] += __expf(s1[ct][r] - 16.f);
          z2L[r] += __expf(s2[ct][r] - 64.f);
        }
      bc = (bc == 5) ? 0 : bc + 1;
      bn = (bn == 5) ? 0 : bn + 1;
    }
  }
  __builtin_amdgcn_s_barrier();  // transition: all pass-1 buffer reads done
  __builtin_amdgcn_sched_barrier(0);

  float rzr[4];
#pragma unroll
  for (int r = 0; r < 4; ++r) {
    float z1 = z1L[r], z2 = z2L[r];
#pragma unroll
    for (int msk = 1; msk < 16; msk <<= 1) {
      z1 += __shfl_xor(z1, msk);
      z2 += __shfl_xor(z2, msk);
    }
    rzr[r] = 1.f / (z1 * z2);
  }

  // pass-2 prologue loads fly while we finish u on the VALU
  stage_kh(0, 0);
  stage_kl(0, 1);
  stage_vt(0, 2);

  // u = q + g, fp16 hi/lo split
  u16x8 uh[2], ul[2];
#pragma unroll
  for (int ks = 0; ks < 2; ++ks)
#pragma unroll
    for (int e = 0; e < 8; ++e) {
      const float u = cvt_back<1>(qh[ks][e]) + gf[ks][e];
      const _Float16 hu = (_Float16)u;
      uh[ks][e] = __builtin_bit_cast(ushort, hu);
      ul[ks][e] = cvt_hi<1>(u - (float)hu);
    }

  f32x4 o[4];
#pragma unroll
  for (int dt = 0; dt < 4; ++dt) { f32x4 z = {0.f, 0.f, 0.f, 0.f}; o[dt] = z; }

  float* wrow = attn + ((size_t)bh * S_ + q0) * S_;
  ushort* wsw = w_s[wv];

  // ---------------- pass 2: exact weights + PV, counted-vmcnt dbuf ----------
  for (int kt = 0; kt < 32; ++kt) {
    if (kt < 31) {
      const int b3 = ((kt + 1) & 1) * 3;
      stage_kh(kt + 1, b3);
      stage_kl(kt + 1, b3 + 1);
      stage_vt(kt + 1, b3 + 2);
      if (kt == 0) asm volatile("s_waitcnt vmcnt(3)" ::: "memory");
      else         asm volatile("s_waitcnt vmcnt(5)" ::: "memory");
    } else {
      asm volatile("s_waitcnt vmcnt(2)" ::: "memory");  // [stage31:3][stores30:2]
    }
    __builtin_amdgcn_sched_barrier(0);
    __builtin_amdgcn_s_barrier();   // tile kt visible to all waves
    __builtin_amdgcn_sched_barrier(0);

    const int c3 = (kt & 1) * 3;
    const ushort* khp = stage_s[c3];
    const ushort* klp = stage_s[c3 + 1];
    const ushort* vtp = stage_s[c3 + 2];

    f32x4 s12[2];
#pragma unroll
    for (int ct = 0; ct < 2; ++ct) {
      f32x4 z = {0.f, 0.f, 0.f, 0.f};
      s12[ct] = z;
#pragma unroll
      for (int ks = 0; ks < 2; ++ks) {
        const u16x8 khf = ldfrag(khp, ct * 16 + lr, ks * 4 + lg);
        const u16x8 klf = ldfrag(klp, ct * 16 + lr, ks * 4 + lg);
        s12[ct] = mfma_t<1>(uh[ks], khf, s12[ct]);
        s12[ct] = mfma_t<1>(uh[ks], klf, s12[ct]);
        s12[ct] = mfma_t<1>(ul[ks], khf, s12[ct]);
      }
    }
    // weights -> wave-private LDS (fp16, swizzled)
#pragma unroll
    for (int ct = 0; ct < 2; ++ct) {
#pragma unroll
      for (int r = 0; r < 4; ++r) {
        const int rowq = lg * 4 + r;
        const int key = ct * 16 + lr;
        const float wv2 = __expf(s12[ct][r] - 80.f) * rzr[r];
        const int ch = (key >> 3) ^ (rowq & 7);
        wsw[rowq * 64 + ch * 8 + (key & 7)] = cvt_hi<1>(wv2);
      }
    }
    // PV (MFMA early; w from own-wave LDS, V pair-packed block tile)
    {
      const u16x8 af = ldfrag(wsw, lr, lg);
#pragma unroll
      for (int dt = 0; dt < 4; ++dt) {
        const u16x8 vf = ldfragP(vtp, dt * 16 + lr, lg);
        o[dt] = mfma_t<1>(af, vf, o[dt]);
      }
    }
    // global fp32 weight store via own-wave LDS transpose (2x dwordx4/lane)
    {
      const int rowq = lane >> 2, cc = lane & 3;
      const int ch = cc ^ (rowq & 7);
      const uint4 wb = *reinterpret_cast<const uint4*>(&wsw[rowq * 64 + ch * 8]);
      const ushort* wp = reinterpret_cast<const ushort*>(&wb);
      float* dst = wrow + (size_t)rowq * S_ + kt * 32 + cc * 8;
      *reinterpret_cast<f4*>(dst) = make_float4(
          cvt_back<1>(wp[0]), cvt_back<1>(wp[1]), cvt_back<1>(wp[2]), cvt_back<1>(wp[3]));
      *reinterpret_cast<f4*>(dst + 4) = make_float4(
          cvt_back<1>(wp[4]), cvt_back<1>(wp[5]), cvt_back<1>(wp[6]), cvt_back<1>(wp[7]));
    }
    __builtin_amdgcn_s_barrier();   // reads done before next-iter overwrite
    __builtin_amdgcn_sched_barrier(0);
  }

  // epilogue: ao[b][s][e] fp16
#pragma unroll
  for (int dt = 0; dt < 4; ++dt)
#pragma unroll
    for (int r = 0; r < 4; ++r)
      aoh[((size_t)b * S_ + q0 + lg * 4 + r) * E_ + h * 64 + dt * 16 + lr] =
          cvt_hi<1>(o[dt][r]);
}

extern "C" void kernel_launch(void* const* d_in, const int* in_sizes, int n_in,
                              void* d_out, int out_size, void* d_ws, size_t ws_size,
                              hipStream_t stream) {
  const float* x  = (const float*)d_in[0];
  const float* ge = (const float*)d_in[1];
  const float* Wq = (const float*)d_in[2];
  const float* bq = (const float*)d_in[3];
  const float* Wk = (const float*)d_in[4];
  const float* bk = (const float*)d_in[5];
  const float* Wv = (const float*)d_in[6];
  const float* bv = (const float*)d_in[7];
  const float* Wo = (const float*)d_in[8];
  const float* bo = (const float*)d_in[9];

  float* out  = (float*)d_out;
  float* attn = out + (size_t)B_ * S_ * E_;

  const size_t MSZ = 1024 * 1024;
  ushort* ws16 = (ushort*)d_ws;  // ~74 MB used (ws ~1 GiB per fill counters)
  ushort* Wqf = ws16 + 0 * MSZ;
  ushort* Wkh = ws16 + 1 * MSZ;
  ushort* Wkl = ws16 + 2 * MSZ;
  ushort* Wvf = ws16 + 3 * MSZ;
  ushort* Wof = ws16 + 4 * MSZ;
  ushort* xf  = ws16 + 5 * MSZ;   // fp16 x
  ushort* xbh = ws16 + 9 * MSZ;   // bf16 x hi
  ushort* xbl = ws16 + 13 * MSZ;  // bf16 x lo
  ushort* qh  = ws16 + 17 * MSZ;  // fp16 q (single, pre-scaled) [B,H,S,HD]
  ushort* kh  = ws16 + 21 * MSZ;  // fp16 k hi [B,H,S,HD]
  ushort* kl  = ws16 + 25 * MSZ;  // fp16 k lo
  ushort* vt  = ws16 + 29 * MSZ;  // fp16 v [B,H,HD,S]
  ushort* aoh = ws16 + 33 * MSZ;  // fp16 ao [B,S,E]

  dim3 blk(256);
  hipLaunchKernelGGL(prep_x, dim3(2048), blk, 0, stream, x, xf, xbh, xbl);
  hipLaunchKernelGGL(prep_w, dim3(16, 16, 4), blk, 0, stream, Wq, Wk, Wv, Wo, ws16);

  dim3 ggrid(E_ / 128, (B_ * S_) / 64);
  // Q: 1-term fp16 (pre-scaled 0.125)
  hipLaunchKernelGGL((gemm_mfma<1, 1, 3>), ggrid, blk, 0, stream,
                     xf, nullptr, Wqf, nullptr, bq, 0.125f, qh, nullptr, nullptr);
  // K: 3-term bf16 (denorm-safe splits), output fp16 hi/lo
  hipLaunchKernelGGL((gemm_mfma<3, 0, 1>), ggrid, blk, 0, stream,
                     xbh, xbl, Wkh, Wkl, bk, 1.0f, kh, kl, nullptr);
  // V: 1-term fp16, transposed output
  hipLaunchKernelGGL((gemm_mfma<1, 1, 2>), ggrid, blk, 0, stream,
                     xf, nullptr, Wvf, nullptr, bv, 1.0f, vt, nullptr, nullptr);

  hipLaunchKernelGGL(attn_mfma, dim3(1024), blk, 0, stream,
                     qh, kh, kl, vt, ge, attn, aoh);

  // O: 1-term fp16 -> fp32 out
  hipLaunchKernelGGL((gemm_mfma<1, 1, 0>), ggrid, blk, 0, stream,
                     aoh, nullptr, Wof, nullptr, bo, 1.0f, nullptr, nullptr, out);
}

// Round 14
// 180.252 us; speedup vs baseline: 1.1835x; 1.1835x over previous
//
#include <hip/hip_runtime.h>
#include <math.h>

#define B_ 4
#define S_ 1024
#define E_ 1024
#define H_ 16
#define HD_ 64

typedef float4 f4;
typedef __bf16 bf16x8 __attribute__((ext_vector_type(8)));
typedef _Float16 f16x8 __attribute__((ext_vector_type(8)));
typedef ushort u16x8 __attribute__((ext_vector_type(8)));
typedef float f32x4 __attribute__((ext_vector_type(4)));

// async global->LDS, 16B per lane. LDS dest = wave-uniform base + lane*16.
__device__ __forceinline__ void gl16(const void* g, void* l) {
  __builtin_amdgcn_global_load_lds(
      (__attribute__((address_space(1))) void*)g,
      (__attribute__((address_space(3))) void*)l, 16, 0, 0);
}

__device__ __forceinline__ ushort f2h(float x) {
  return __builtin_bit_cast(ushort, (_Float16)x);
}
__device__ __forceinline__ float h2f(ushort h) {
  return (float)__builtin_bit_cast(_Float16, h);
}
__device__ __forceinline__ f32x4 mfma16(u16x8 a, u16x8 b, f32x4 c) {
  return __builtin_amdgcn_mfma_f32_16x16x32_f16(
      __builtin_bit_cast(f16x8, a), __builtin_bit_cast(f16x8, b), c, 0, 0, 0);
}
// frag load, full-row layout: row stride 64 ushorts, chunk XOR row&7 (8 slots).
__device__ __forceinline__ u16x8 ldfrag(const ushort* s, int row, int chunk) {
  return *reinterpret_cast<const u16x8*>(s + row * 64 + ((chunk ^ (row & 7)) << 3));
}
// frag load, row stride 32 ushorts (vt tiles, 4 chunks/row)
__device__ __forceinline__ u16x8 ldfrag32(const ushort* s, int row, int chunk) {
  return *reinterpret_cast<const u16x8*>(s + row * 32 + ((chunk ^ (row & 3)) << 3));
}

// ws16 layout (units of MSZ = 1M ushorts = 2 MB):
// 0:Wqf 1:Wkf 2:Wvf 3:Wof  4..7:xf  8..11:qh  12..15:kf  16..19:vt  20..23:aoh

// ---------------------------------------------------------------------------
// prep_x: x fp32 -> fp16
// ---------------------------------------------------------------------------
__global__ __launch_bounds__(256) void prep_x(
    const float* __restrict__ x, ushort* __restrict__ xf)
{
  const size_t i = ((size_t)blockIdx.x * 256 + threadIdx.x) * 8;
  float v[8];
  *reinterpret_cast<f4*>(v)     = *reinterpret_cast<const f4*>(x + i);
  *reinterpret_cast<f4*>(v + 4) = *reinterpret_cast<const f4*>(x + i + 4);
  unsigned fw[4];
#pragma unroll
  for (int p = 0; p < 4; ++p)
    fw[p] = (unsigned)f2h(v[2 * p]) | ((unsigned)f2h(v[2 * p + 1]) << 16);
  *reinterpret_cast<uint4*>(xf + i) = make_uint4(fw[0], fw[1], fw[2], fw[3]);
}

// ---------------------------------------------------------------------------
// prep_w: W fp32 [k][n] -> transposed fp16 Wt[n][k] (all four matrices).
// ---------------------------------------------------------------------------
__global__ __launch_bounds__(256) void prep_w(
    const float* __restrict__ Wq, const float* __restrict__ Wk,
    const float* __restrict__ Wv, const float* __restrict__ Wo,
    ushort* __restrict__ ws16)
{
  const int MSZ = 1024 * 1024;
  const int mat = blockIdx.z;
  const int n0 = blockIdx.x * 64, k0 = blockIdx.y * 64;
  const float* W = mat == 0 ? Wq : mat == 1 ? Wk : mat == 2 ? Wv : Wo;
  ushort* Oh = ws16 + (size_t)mat * MSZ;

  __shared__ __align__(16) float tile[64][65];
  const int t = threadIdx.x;
  const int r = t >> 2, cq = t & 3;
#pragma unroll
  for (int j = 0; j < 4; ++j) {
    const f4 v = *reinterpret_cast<const f4*>(&W[(size_t)(k0 + r) * 1024 + n0 + cq * 16 + 4 * j]);
    tile[r][cq * 16 + 4 * j + 0] = v.x;
    tile[r][cq * 16 + 4 * j + 1] = v.y;
    tile[r][cq * 16 + 4 * j + 2] = v.z;
    tile[r][cq * 16 + 4 * j + 3] = v.w;
  }
  __syncthreads();
  unsigned hw[8];
#pragma unroll
  for (int p = 0; p < 8; ++p)
    hw[p] = (unsigned)f2h(tile[cq * 16 + 2 * p][r]) |
            ((unsigned)f2h(tile[cq * 16 + 2 * p + 1][r]) << 16);
  ushort* dh = Oh + (size_t)(n0 + r) * 1024 + k0 + cq * 16;
  *reinterpret_cast<uint4*>(dh)     = make_uint4(hw[0], hw[1], hw[2], hw[3]);
  *reinterpret_cast<uint4*>(dh + 8) = make_uint4(hw[4], hw[5], hw[6], hw[7]);
}

// ---------------------------------------------------------------------------
// MFMA GEMM (R6/R12 structure, single-buffered): C = A @ Wt^T + bias.
// Tile 64(M) x 128(N), BK=64, fp16 1-term. All staging via global_load_lds.
// OMODE 0: fp32 [m][n]; 2: fp16 [B,H,HD,S]; 3: fp16 [B,H,S,HD].
// ---------------------------------------------------------------------------
template <int OMODE>
__global__ __launch_bounds__(256) void gemm_mfma(
    const ushort* __restrict__ Ab, const ushort* __restrict__ Bhg,
    const float* __restrict__ bias, float scale,
    ushort* __restrict__ Oh, float* __restrict__ Of)
{
  const int n0 = blockIdx.x * 128;
  const int m0 = blockIdx.y * 64;
  const int t = threadIdx.x;
  const int wv = t >> 6, lane = t & 63;
  const int lr = lane & 15, lg = lane >> 4;
  const int wm = (wv >> 1) * 32, wn = (wv & 1) * 64;
  const int row8 = lane >> 3, ch8 = lane & 7;

  __shared__ __align__(16) ushort Ah_s[64 * 64];
  __shared__ __align__(16) ushort Bh_s[128 * 64];
  __shared__ __align__(16) ushort tr_s[OMODE == 2 ? 128 * 72 : 16];

  f32x4 acc[2][4];
#pragma unroll
  for (int mi = 0; mi < 2; ++mi)
#pragma unroll
    for (int ni = 0; ni < 4; ++ni) { f32x4 z = {0.f, 0.f, 0.f, 0.f}; acc[mi][ni] = z; }

  for (int kt = 0; kt < 16; ++kt) {
    const int k0 = kt * 64;
    __syncthreads();
#pragma unroll
    for (int j = 0; j < 4; ++j) {
      const int row = wv * 32 + j * 8 + row8;
      gl16(Bhg + (size_t)(n0 + row) * 1024 + k0 + ((ch8 ^ (row & 7)) << 3),
           &Bh_s[(wv * 32 + j * 8) * 64]);
    }
#pragma unroll
    for (int j = 0; j < 2; ++j) {
      const int row = wv * 16 + j * 8 + row8;
      gl16(Ab + (size_t)(m0 + row) * 1024 + k0 + ((ch8 ^ (row & 7)) << 3),
           &Ah_s[(wv * 16 + j * 8) * 64]);
    }
    __syncthreads();
#pragma unroll
    for (int ks = 0; ks < 2; ++ks) {
      const u16x8 ah0 = ldfrag(Ah_s, wm + lr, ks * 4 + lg);
      const u16x8 ah1 = ldfrag(Ah_s, wm + 16 + lr, ks * 4 + lg);
#pragma unroll
      for (int ni = 0; ni < 4; ++ni) {
        const u16x8 bh = ldfrag(Bh_s, wn + ni * 16 + lr, ks * 4 + lg);
        acc[0][ni] = mfma16(ah0, bh, acc[0][ni]);
        acc[1][ni] = mfma16(ah1, bh, acc[1][ni]);
      }
    }
  }

  // ---- epilogue ----
  if constexpr (OMODE == 2) {
    __syncthreads();
#pragma unroll
    for (int mi = 0; mi < 2; ++mi)
#pragma unroll
      for (int ni = 0; ni < 4; ++ni)
#pragma unroll
        for (int r = 0; r < 4; ++r) {
          const int n_l = wn + ni * 16 + lr, m_l = wm + mi * 16 + lg * 4 + r;
          tr_s[n_l * 72 + m_l] = f2h(acc[mi][ni][r] + bias[n0 + n_l]);
        }
    __syncthreads();
    const int row = t >> 1, hf = t & 1;
    const int n_g = n0 + row;
    const int h_ = n_g >> 6, hd = n_g & 63;
    const int b_g = m0 >> 10;
    ushort* dst = Oh + ((size_t)(b_g * 16 + h_) * 64 + hd) * 1024 + (m0 & 1023) + hf * 32;
#pragma unroll
    for (int j = 0; j < 4; ++j)
      *reinterpret_cast<uint4*>(dst + 8 * j) =
          *reinterpret_cast<const uint4*>(&tr_s[row * 72 + hf * 32 + 8 * j]);
  } else {
#pragma unroll
    for (int mi = 0; mi < 2; ++mi)
#pragma unroll
      for (int ni = 0; ni < 4; ++ni) {
        const int n = n0 + wn + ni * 16 + lr;
        const float bi = bias[n];
#pragma unroll
        for (int r = 0; r < 4; ++r) {
          const int m = m0 + wm + mi * 16 + lg * 4 + r;
          const float v = (acc[mi][ni][r] + bi) * scale;
          if constexpr (OMODE == 0) {
            Of[(size_t)m * 1024 + n] = v;
          } else {  // OMODE == 3
            const size_t addr =
                ((size_t)((m >> 10) * 16 + (n >> 6)) * 1024 + (m & 1023)) * 64 + (n & 63);
            Oh[addr] = f2h(v);
          }
        }
      }
  }
}

// ---------------------------------------------------------------------------
// MFMA dual-softmax attention: counted-vmcnt pipeline (R12 scheme), KVBLK=32,
// single-fp16 K (no kl stream) -> LDS 24KB, 6 blocks/CU.
// pass1: 1 load/iter -> vmcnt(1/0); pass2: 2 loads + 2 stores/iter ->
// vmcnt(2/4/2). Stores never waited on.
// ---------------------------------------------------------------------------
__global__ __launch_bounds__(256) void attn_mfma(
    const ushort* __restrict__ qh_g, const ushort* __restrict__ kf_g,
    const ushort* __restrict__ vt_g, const float* __restrict__ ge,
    float* __restrict__ attn, ushort* __restrict__ aoh)
{
  __shared__ __align__(16) ushort kh2_s[2][2048];
  __shared__ __align__(16) ushort vt2_s[2][2048];
  __shared__ __align__(16) ushort w_s[4][1024];

  const int bid = blockIdx.x;
  const int wg = (bid & 7) * 128 + (bid >> 3);  // bijective XCD swizzle (1024 = 8*128)
  const int bh = wg >> 4, qb = wg & 15;
  const int b = bh >> 4, h = bh & 15;

  const int t = threadIdx.x;
  const int wv = t >> 6, lane = t & 63;
  const int lr = lane & 15, lg = lane >> 4;
  const int q0 = qb * 64 + wv * 16;

  // Q (fp16, pre-scaled 0.125) + G (fp32 kept for u; fp16-hi for pass 1)
  u16x8 qh[2], gh[2];
  float gf[2][8];
#pragma unroll
  for (int ks = 0; ks < 2; ++ks) {
    const size_t qoff = ((size_t)bh * S_ + q0 + lr) * HD_ + ks * 32 + lg * 8;
    qh[ks] = *reinterpret_cast<const u16x8*>(qh_g + qoff);
    const float* grow = ge + ((size_t)b * S_ + q0 + lr) * HD_ + ks * 32 + lg * 8;
    *reinterpret_cast<f4*>(&gf[ks][0]) = *reinterpret_cast<const f4*>(grow);
    *reinterpret_cast<f4*>(&gf[ks][4]) = *reinterpret_cast<const f4*>(grow + 4);
#pragma unroll
    for (int e = 0; e < 8; ++e) gh[ks][e] = f2h(gf[ks][e]);
  }

  const ushort* kfb = kf_g + (size_t)bh * S_ * HD_;
  const ushort* vtb = vt_g + (size_t)bh * HD_ * S_;

  // per-wave staging geometry (tile = 32 keys x 64 d for K; 64 d x 32 keys V)
  const int krow = wv * 8 + (lane >> 3);           // K tile row (key), 8/wave
  const int ksw  = ((lane & 7) ^ (krow & 7)) << 3; // pre-swizzled source chunk
  const int vrow = wv * 16 + (lane >> 2);          // V tile row (d), 16/wave
  const int vsw  = ((lane & 3) ^ (vrow & 3)) << 3;

  auto stage_kf = [&](int kt, int c) {
    gl16(kfb + kt * 2048 + krow * 64 + ksw, &kh2_s[c][wv * 512]);
  };
  auto stage_vt = [&](int kt, int c) {
    gl16(vtb + kt * 32 + (size_t)vrow * 1024 + vsw, &vt2_s[c][wv * 512]);
  };

  float z1L[4] = {0.f, 0.f, 0.f, 0.f}, z2L[4] = {0.f, 0.f, 0.f, 0.f};

  // drain Q/G loads so vmcnt bookkeeping below is exact
  asm volatile("s_waitcnt vmcnt(0)" ::: "memory");
  __builtin_amdgcn_sched_barrier(0);

  // ---------------- pass 1: z-sums, counted-vmcnt dbuf ----------------------
  stage_kf(0, 0);
  for (int kt = 0; kt < 32; ++kt) {
    if (kt < 31) {
      stage_kf(kt + 1, (kt + 1) & 1);
      asm volatile("s_waitcnt vmcnt(1)" ::: "memory");
    } else {
      asm volatile("s_waitcnt vmcnt(0)" ::: "memory");
    }
    __builtin_amdgcn_sched_barrier(0);
    __builtin_amdgcn_s_barrier();   // all waves staged -> tile kt visible
    __builtin_amdgcn_sched_barrier(0);

    const ushort* kp = kh2_s[kt & 1];
    f32x4 s1[2], s2[2];
#pragma unroll
    for (int ct = 0; ct < 2; ++ct) {
      f32x4 z = {0.f, 0.f, 0.f, 0.f};
      s1[ct] = z; s2[ct] = z;
#pragma unroll
      for (int ks = 0; ks < 2; ++ks) {
        const u16x8 kf = ldfrag(kp, ct * 16 + lr, ks * 4 + lg);
        s1[ct] = mfma16(qh[ks], kf, s1[ct]);
        s2[ct] = mfma16(gh[ks], kf, s2[ct]);
      }
    }
#pragma unroll
    for (int r = 0; r < 4; ++r)
#pragma unroll
      for (int ct = 0; ct < 2; ++ct) {
        z1L[r] += __expf(s1[ct][r] - 16.f);
        z2L[r] += __expf(s2[ct][r] - 64.f);
      }
    __builtin_amdgcn_s_barrier();   // all waves done reading buf before overwrite
    __builtin_amdgcn_sched_barrier(0);
  }

  float rzr[4];
#pragma unroll
  for (int r = 0; r < 4; ++r) {
    float z1 = z1L[r], z2 = z2L[r];
#pragma unroll
    for (int msk = 1; msk < 16; msk <<= 1) {
      z1 += __shfl_xor(z1, msk);
      z2 += __shfl_xor(z2, msk);
    }
    rzr[r] = 1.f / (z1 * z2);
  }

  // pass-2 prologue loads fly while we finish u on the VALU
  stage_kf(0, 0);
  stage_vt(0, 0);

  // u = q + g, fp16 hi/lo split
  u16x8 uh[2], ul[2];
#pragma unroll
  for (int ks = 0; ks < 2; ++ks)
#pragma unroll
    for (int e = 0; e < 8; ++e) {
      const float u = h2f(qh[ks][e]) + gf[ks][e];
      const _Float16 hu = (_Float16)u;
      uh[ks][e] = __builtin_bit_cast(ushort, hu);
      ul[ks][e] = f2h(u - (float)hu);
    }

  f32x4 o[4];
#pragma unroll
  for (int dt = 0; dt < 4; ++dt) { f32x4 z = {0.f, 0.f, 0.f, 0.f}; o[dt] = z; }

  float* wrow = attn + ((size_t)bh * S_ + q0) * S_;
  ushort* wsw = w_s[wv];

  // ---------------- pass 2: exact weights + PV, counted-vmcnt dbuf ----------
  for (int kt = 0; kt < 32; ++kt) {
    if (kt < 31) {
      stage_kf(kt + 1, (kt + 1) & 1);
      stage_vt(kt + 1, (kt + 1) & 1);
      // outstanding: [stage kt:2][stores kt-1:2][stage kt+1:2] -> oldest 2 go
      if (kt == 0) asm volatile("s_waitcnt vmcnt(2)" ::: "memory");
      else         asm volatile("s_waitcnt vmcnt(4)" ::: "memory");
    } else {
      asm volatile("s_waitcnt vmcnt(2)" ::: "memory");  // [stage31:2][stores30:2]
    }
    __builtin_amdgcn_sched_barrier(0);
    __builtin_amdgcn_s_barrier();   // tile kt visible to all waves
    __builtin_amdgcn_sched_barrier(0);

    const int c = kt & 1;
    const ushort* kfp = kh2_s[c];
    const ushort* vtp = vt2_s[c];

    f32x4 s12[2];
#pragma unroll
    for (int ct = 0; ct < 2; ++ct) {
      f32x4 z = {0.f, 0.f, 0.f, 0.f};
      s12[ct] = z;
#pragma unroll
      for (int ks = 0; ks < 2; ++ks) {
        const u16x8 kf = ldfrag(kfp, ct * 16 + lr, ks * 4 + lg);
        s12[ct] = mfma16(uh[ks], kf, s12[ct]);
        s12[ct] = mfma16(ul[ks], kf, s12[ct]);
      }
    }
    // weights -> wave-private LDS (fp16, swizzled; keys 0..31 in chunks 0..3)
#pragma unroll
    for (int ct = 0; ct < 2; ++ct) {
#pragma unroll
      for (int r = 0; r < 4; ++r) {
        const int rowq = lg * 4 + r;
        const int key = ct * 16 + lr;
        const float wv2 = __expf(s12[ct][r] - 80.f) * rzr[r];
        const int ch = (key >> 3) ^ (rowq & 7);
        wsw[rowq * 64 + ch * 8 + (key & 7)] = f2h(wv2);
      }
    }
    // PV (MFMA early; w from own-wave LDS, V from block tile)
    {
      const u16x8 af = ldfrag(wsw, lr, lg);
#pragma unroll
      for (int dt = 0; dt < 4; ++dt) {
        const u16x8 vf = ldfrag32(vtp, dt * 16 + lr, lg);
        o[dt] = mfma16(af, vf, o[dt]);
      }
    }
    // global fp32 weight store via own-wave LDS transpose (2x dwordx4/lane)
    {
      const int rowq = lane >> 2, cc = lane & 3;
      const int ch = cc ^ (rowq & 7);
      const uint4 wb = *reinterpret_cast<const uint4*>(&wsw[rowq * 64 + ch * 8]);
      const ushort* wp = reinterpret_cast<const ushort*>(&wb);
      float* dst = wrow + (size_t)rowq * S_ + kt * 32 + cc * 8;
      *reinterpret_cast<f4*>(dst) = make_float4(
          h2f(wp[0]), h2f(wp[1]), h2f(wp[2]), h2f(wp[3]));
      *reinterpret_cast<f4*>(dst + 4) = make_float4(
          h2f(wp[4]), h2f(wp[5]), h2f(wp[6]), h2f(wp[7]));
    }
    __builtin_amdgcn_s_barrier();   // all waves done reading buf before overwrite
    __builtin_amdgcn_sched_barrier(0);
  }

  // epilogue: ao[b][s][e] fp16
#pragma unroll
  for (int dt = 0; dt < 4; ++dt)
#pragma unroll
    for (int r = 0; r < 4; ++r)
      aoh[((size_t)b * S_ + q0 + lg * 4 + r) * E_ + h * 64 + dt * 16 + lr] =
          f2h(o[dt][r]);
}

extern "C" void kernel_launch(void* const* d_in, const int* in_sizes, int n_in,
                              void* d_out, int out_size, void* d_ws, size_t ws_size,
                              hipStream_t stream) {
  const float* x  = (const float*)d_in[0];
  const float* ge = (const float*)d_in[1];
  const float* Wq = (const float*)d_in[2];
  const float* bq = (const float*)d_in[3];
  const float* Wk = (const float*)d_in[4];
  const float* bk = (const float*)d_in[5];
  const float* Wv = (const float*)d_in[6];
  const float* bv = (const float*)d_in[7];
  const float* Wo = (const float*)d_in[8];
  const float* bo = (const float*)d_in[9];

  float* out  = (float*)d_out;
  float* attn = out + (size_t)B_ * S_ * E_;

  const size_t MSZ = 1024 * 1024;
  ushort* ws16 = (ushort*)d_ws;  // 48 MB used (ws ~1 GiB per fill counters)
  ushort* Wqf = ws16 + 0 * MSZ;
  ushort* Wkf = ws16 + 1 * MSZ;
  ushort* Wvf = ws16 + 2 * MSZ;
  ushort* Wof = ws16 + 3 * MSZ;
  ushort* xf  = ws16 + 4 * MSZ;   // fp16 x
  ushort* qh  = ws16 + 8 * MSZ;   // fp16 q (single, pre-scaled) [B,H,S,HD]
  ushort* kf  = ws16 + 12 * MSZ;  // fp16 k (single) [B,H,S,HD]
  ushort* vt  = ws16 + 16 * MSZ;  // fp16 v [B,H,HD,S]
  ushort* aoh = ws16 + 20 * MSZ;  // fp16 ao [B,S,E]

  dim3 blk(256);
  hipLaunchKernelGGL(prep_x, dim3(2048), blk, 0, stream, x, xf);
  hipLaunchKernelGGL(prep_w, dim3(16, 16, 4), blk, 0, stream, Wq, Wk, Wv, Wo, ws16);

  dim3 ggrid(E_ / 128, (B_ * S_) / 64);
  // Q: 1-term fp16 (pre-scaled 0.125)
  hipLaunchKernelGGL((gemm_mfma<3>), ggrid, blk, 0, stream,
                     xf, Wqf, bq, 0.125f, qh, nullptr);
  // K: 1-term fp16 (budgeted: delta-logit ~6e-3, ~2x margin on out0 threshold)
  hipLaunchKernelGGL((gemm_mfma<3>), ggrid, blk, 0, stream,
                     xf, Wkf, bk, 1.0f, kf, nullptr);
  // V: 1-term fp16, transposed output
  hipLaunchKernelGGL((gemm_mfma<2>), ggrid, blk, 0, stream,
                     xf, Wvf, bv, 1.0f, vt, nullptr);

  hipLaunchKernelGGL(attn_mfma, dim3(1024), blk, 0, stream,
                     qh, kf, vt, ge, attn, aoh);

  // O: 1-term fp16 -> fp32 out
  hipLaunchKernelGGL((gemm_mfma<0>), ggrid, blk, 0, stream,
                     aoh, Wof, bo, 1.0f, nullptr, out);
}

// Round 16
// 180.147 us; speedup vs baseline: 1.1842x; 1.0006x over previous
//
#include <hip/hip_runtime.h>
#include <math.h>

#define B_ 4
#define S_ 1024
#define E_ 1024
#define H_ 16
#define HD_ 64

#define LOG2E 1.4426950408889634f
#define C16L2 23.08312065422341f    // 16*log2e
#define C64L2 92.33248261689365f    // 64*log2e
#define C80L2 115.41560327111706f   // 80*log2e

typedef float4 f4;
typedef _Float16 f16x8 __attribute__((ext_vector_type(8)));
typedef ushort u16x8 __attribute__((ext_vector_type(8)));
typedef float f32x4 __attribute__((ext_vector_type(4)));

// async global->LDS, 16B per lane. LDS dest = wave-uniform base + lane*16.
__device__ __forceinline__ void gl16(const void* g, void* l) {
  __builtin_amdgcn_global_load_lds(
      (__attribute__((address_space(1))) void*)g,
      (__attribute__((address_space(3))) void*)l, 16, 0, 0);
}

__device__ __forceinline__ ushort f2h(float x) {
  return __builtin_bit_cast(ushort, (_Float16)x);
}
__device__ __forceinline__ float h2f(ushort h) {
  return (float)__builtin_bit_cast(_Float16, h);
}
// raw v_exp_f32 (2^x), avoiding glibc's __exp2f macro collision
__device__ __forceinline__ float exp2r(float x) {
  return __builtin_amdgcn_exp2f(x);
}
__device__ __forceinline__ f32x4 mfma16(u16x8 a, u16x8 b, f32x4 c) {
  return __builtin_amdgcn_mfma_f32_16x16x32_f16(
      __builtin_bit_cast(f16x8, a), __builtin_bit_cast(f16x8, b), c, 0, 0, 0);
}
// frag load, full-row layout: row stride 64 ushorts, chunk XOR row&7 (8 slots).
__device__ __forceinline__ u16x8 ldfrag(const ushort* s, int row, int chunk) {
  return *reinterpret_cast<const u16x8*>(s + row * 64 + ((chunk ^ (row & 7)) << 3));
}
// frag load, row stride 32 ushorts (vt tiles, 4 chunks/row)
__device__ __forceinline__ u16x8 ldfrag32(const ushort* s, int row, int chunk) {
  return *reinterpret_cast<const u16x8*>(s + row * 32 + ((chunk ^ (row & 3)) << 3));
}

// ws16 layout (units of MSZ = 1M ushorts = 2 MB):
// 0:Wqf 1:Wkf 2:Wvf 3:Wof  4..7:xf  8..11:qh  12..15:kf  16..19:vt  20..23:aoh

// ---------------------------------------------------------------------------
// prep_x: x fp32 -> fp16
// ---------------------------------------------------------------------------
__global__ __launch_bounds__(256) void prep_x(
    const float* __restrict__ x, ushort* __restrict__ xf)
{
  const size_t i = ((size_t)blockIdx.x * 256 + threadIdx.x) * 8;
  float v[8];
  *reinterpret_cast<f4*>(v)     = *reinterpret_cast<const f4*>(x + i);
  *reinterpret_cast<f4*>(v + 4) = *reinterpret_cast<const f4*>(x + i + 4);
  unsigned fw[4];
#pragma unroll
  for (int p = 0; p < 4; ++p)
    fw[p] = (unsigned)f2h(v[2 * p]) | ((unsigned)f2h(v[2 * p + 1]) << 16);
  *reinterpret_cast<uint4*>(xf + i) = make_uint4(fw[0], fw[1], fw[2], fw[3]);
}

// ---------------------------------------------------------------------------
// prep_w: W fp32 [k][n] -> transposed fp16 Wt[n][k] (all four matrices).
// ---------------------------------------------------------------------------
__global__ __launch_bounds__(256) void prep_w(
    const float* __restrict__ Wq, const float* __restrict__ Wk,
    const float* __restrict__ Wv, const float* __restrict__ Wo,
    ushort* __restrict__ ws16)
{
  const int MSZ = 1024 * 1024;
  const int mat = blockIdx.z;
  const int n0 = blockIdx.x * 64, k0 = blockIdx.y * 64;
  const float* W = mat == 0 ? Wq : mat == 1 ? Wk : mat == 2 ? Wv : Wo;
  ushort* Oh = ws16 + (size_t)mat * MSZ;

  __shared__ __align__(16) float tile[64][65];
  const int t = threadIdx.x;
  const int r = t >> 2, cq = t & 3;
#pragma unroll
  for (int j = 0; j < 4; ++j) {
    const f4 v = *reinterpret_cast<const f4*>(&W[(size_t)(k0 + r) * 1024 + n0 + cq * 16 + 4 * j]);
    tile[r][cq * 16 + 4 * j + 0] = v.x;
    tile[r][cq * 16 + 4 * j + 1] = v.y;
    tile[r][cq * 16 + 4 * j + 2] = v.z;
    tile[r][cq * 16 + 4 * j + 3] = v.w;
  }
  __syncthreads();
  unsigned hw[8];
#pragma unroll
  for (int p = 0; p < 8; ++p)
    hw[p] = (unsigned)f2h(tile[cq * 16 + 2 * p][r]) |
            ((unsigned)f2h(tile[cq * 16 + 2 * p + 1][r]) << 16);
  ushort* dh = Oh + (size_t)(n0 + r) * 1024 + k0 + cq * 16;
  *reinterpret_cast<uint4*>(dh)     = make_uint4(hw[0], hw[1], hw[2], hw[3]);
  *reinterpret_cast<uint4*>(dh + 8) = make_uint4(hw[4], hw[5], hw[6], hw[7]);
}

// ---------------------------------------------------------------------------
// MFMA GEMM (R6/R12 structure, single-buffered): C = A @ Wt^T + bias.
// Tile 64(M) x 128(N), BK=64, fp16 1-term. All staging via global_load_lds.
// OMODE 0: fp32 [m][n]; 2: fp16 [B,H,HD,S]; 3: fp16 [B,H,S,HD].
// ---------------------------------------------------------------------------
template <int OMODE>
__global__ __launch_bounds__(256) void gemm_mfma(
    const ushort* __restrict__ Ab, const ushort* __restrict__ Bhg,
    const float* __restrict__ bias, float scale,
    ushort* __restrict__ Oh, float* __restrict__ Of)
{
  const int n0 = blockIdx.x * 128;
  const int m0 = blockIdx.y * 64;
  const int t = threadIdx.x;
  const int wv = t >> 6, lane = t & 63;
  const int lr = lane & 15, lg = lane >> 4;
  const int wm = (wv >> 1) * 32, wn = (wv & 1) * 64;
  const int row8 = lane >> 3, ch8 = lane & 7;

  __shared__ __align__(16) ushort Ah_s[64 * 64];
  __shared__ __align__(16) ushort Bh_s[128 * 64];
  __shared__ __align__(16) ushort tr_s[OMODE == 2 ? 128 * 72 : 16];

  f32x4 acc[2][4];
#pragma unroll
  for (int mi = 0; mi < 2; ++mi)
#pragma unroll
    for (int ni = 0; ni < 4; ++ni) { f32x4 z = {0.f, 0.f, 0.f, 0.f}; acc[mi][ni] = z; }

  for (int kt = 0; kt < 16; ++kt) {
    const int k0 = kt * 64;
    __syncthreads();
#pragma unroll
    for (int j = 0; j < 4; ++j) {
      const int row = wv * 32 + j * 8 + row8;
      gl16(Bhg + (size_t)(n0 + row) * 1024 + k0 + ((ch8 ^ (row & 7)) << 3),
           &Bh_s[(wv * 32 + j * 8) * 64]);
    }
#pragma unroll
    for (int j = 0; j < 2; ++j) {
      const int row = wv * 16 + j * 8 + row8;
      gl16(Ab + (size_t)(m0 + row) * 1024 + k0 + ((ch8 ^ (row & 7)) << 3),
           &Ah_s[(wv * 16 + j * 8) * 64]);
    }
    __syncthreads();
#pragma unroll
    for (int ks = 0; ks < 2; ++ks) {
      const u16x8 ah0 = ldfrag(Ah_s, wm + lr, ks * 4 + lg);
      const u16x8 ah1 = ldfrag(Ah_s, wm + 16 + lr, ks * 4 + lg);
#pragma unroll
      for (int ni = 0; ni < 4; ++ni) {
        const u16x8 bh = ldfrag(Bh_s, wn + ni * 16 + lr, ks * 4 + lg);
        acc[0][ni] = mfma16(ah0, bh, acc[0][ni]);
        acc[1][ni] = mfma16(ah1, bh, acc[1][ni]);
      }
    }
  }

  // ---- epilogue ----
  if constexpr (OMODE == 2) {
    __syncthreads();
#pragma unroll
    for (int mi = 0; mi < 2; ++mi)
#pragma unroll
      for (int ni = 0; ni < 4; ++ni)
#pragma unroll
        for (int r = 0; r < 4; ++r) {
          const int n_l = wn + ni * 16 + lr, m_l = wm + mi * 16 + lg * 4 + r;
          tr_s[n_l * 72 + m_l] = f2h(acc[mi][ni][r] + bias[n0 + n_l]);
        }
    __syncthreads();
    const int row = t >> 1, hf = t & 1;
    const int n_g = n0 + row;
    const int h_ = n_g >> 6, hd = n_g & 63;
    const int b_g = m0 >> 10;
    ushort* dst = Oh + ((size_t)(b_g * 16 + h_) * 64 + hd) * 1024 + (m0 & 1023) + hf * 32;
#pragma unroll
    for (int j = 0; j < 4; ++j)
      *reinterpret_cast<uint4*>(dst + 8 * j) =
          *reinterpret_cast<const uint4*>(&tr_s[row * 72 + hf * 32 + 8 * j]);
  } else {
#pragma unroll
    for (int mi = 0; mi < 2; ++mi)
#pragma unroll
      for (int ni = 0; ni < 4; ++ni) {
        const int n = n0 + wn + ni * 16 + lr;
        const float bi = bias[n];
#pragma unroll
        for (int r = 0; r < 4; ++r) {
          const int m = m0 + wm + mi * 16 + lg * 4 + r;
          const float v = (acc[mi][ni][r] + bi) * scale;
          if constexpr (OMODE == 0) {
            Of[(size_t)m * 1024 + n] = v;
          } else {  // OMODE == 3
            const size_t addr =
                ((size_t)((m >> 10) * 16 + (n >> 6)) * 1024 + (m & 1023)) * 64 + (n & 63);
            Oh[addr] = f2h(v);
          }
        }
      }
  }
}

// ---------------------------------------------------------------------------
// MFMA dual-softmax attention: counted-vmcnt pipeline, KVBLK=32, 6 blocks/CU.
// All logits in log2 units (q pre-scaled by 0.125*log2e, g by log2e) ->
// exps are raw v_exp_f32. Pass-2 u = q'+g' single fp16 (budget: ~0.2% weight
// rel err vs 2.8%-of-max threshold). pass1: vmcnt(1/0); pass2: vmcnt(2/4/2).
// ---------------------------------------------------------------------------
__global__ __launch_bounds__(256) void attn_mfma(
    const ushort* __restrict__ qh_g, const ushort* __restrict__ kf_g,
    const ushort* __restrict__ vt_g, const float* __restrict__ ge,
    float* __restrict__ attn, ushort* __restrict__ aoh)
{
  __shared__ __align__(16) ushort kh2_s[2][2048];
  __shared__ __align__(16) ushort vt2_s[2][2048];
  __shared__ __align__(16) ushort w_s[4][1024];

  const int bid = blockIdx.x;
  const int wg = (bid & 7) * 128 + (bid >> 3);  // bijective XCD swizzle (1024 = 8*128)
  const int bh = wg >> 4, qb = wg & 15;
  const int b = bh >> 4, h = bh & 15;

  const int t = threadIdx.x;
  const int wv = t >> 6, lane = t & 63;
  const int lr = lane & 15, lg = lane >> 4;
  const int q0 = qb * 64 + wv * 16;

  // Q (fp16, pre-scaled 0.125*log2e) + G (fp32*log2e kept; fp16 for pass 1)
  u16x8 qh[2], gh[2];
  float gf[2][8];
#pragma unroll
  for (int ks = 0; ks < 2; ++ks) {
    const size_t qoff = ((size_t)bh * S_ + q0 + lr) * HD_ + ks * 32 + lg * 8;
    qh[ks] = *reinterpret_cast<const u16x8*>(qh_g + qoff);
    const float* grow = ge + ((size_t)b * S_ + q0 + lr) * HD_ + ks * 32 + lg * 8;
    f4 g0 = *reinterpret_cast<const f4*>(grow);
    f4 g1 = *reinterpret_cast<const f4*>(grow + 4);
    gf[ks][0] = g0.x * LOG2E; gf[ks][1] = g0.y * LOG2E;
    gf[ks][2] = g0.z * LOG2E; gf[ks][3] = g0.w * LOG2E;
    gf[ks][4] = g1.x * LOG2E; gf[ks][5] = g1.y * LOG2E;
    gf[ks][6] = g1.z * LOG2E; gf[ks][7] = g1.w * LOG2E;
#pragma unroll
    for (int e = 0; e < 8; ++e) gh[ks][e] = f2h(gf[ks][e]);
  }

  const ushort* kfb = kf_g + (size_t)bh * S_ * HD_;
  const ushort* vtb = vt_g + (size_t)bh * HD_ * S_;

  // per-wave staging geometry (tile = 32 keys x 64 d for K; 64 d x 32 keys V)
  const int krow = wv * 8 + (lane >> 3);
  const int ksw  = ((lane & 7) ^ (krow & 7)) << 3;
  const int vrow = wv * 16 + (lane >> 2);
  const int vsw  = ((lane & 3) ^ (vrow & 3)) << 3;

  auto stage_kf = [&](int kt, int c) {
    gl16(kfb + kt * 2048 + krow * 64 + ksw, &kh2_s[c][wv * 512]);
  };
  auto stage_vt = [&](int kt, int c) {
    gl16(vtb + kt * 32 + (size_t)vrow * 1024 + vsw, &vt2_s[c][wv * 512]);
  };

  float z1L[4] = {0.f, 0.f, 0.f, 0.f}, z2L[4] = {0.f, 0.f, 0.f, 0.f};

  // drain Q/G loads so vmcnt bookkeeping below is exact
  asm volatile("s_waitcnt vmcnt(0)" ::: "memory");
  __builtin_amdgcn_sched_barrier(0);

  // ---------------- pass 1: z-sums, counted-vmcnt dbuf ----------------------
  stage_kf(0, 0);
  for (int kt = 0; kt < 32; ++kt) {
    if (kt < 31) {
      stage_kf(kt + 1, (kt + 1) & 1);
      asm volatile("s_waitcnt vmcnt(1)" ::: "memory");
    } else {
      asm volatile("s_waitcnt vmcnt(0)" ::: "memory");
    }
    __builtin_amdgcn_sched_barrier(0);
    __builtin_amdgcn_s_barrier();   // all waves staged -> tile kt visible
    __builtin_amdgcn_sched_barrier(0);

    const ushort* kp = kh2_s[kt & 1];
    f32x4 s1[2], s2[2];
#pragma unroll
    for (int ct = 0; ct < 2; ++ct) {
      f32x4 z = {0.f, 0.f, 0.f, 0.f};
      s1[ct] = z; s2[ct] = z;
#pragma unroll
      for (int ks = 0; ks < 2; ++ks) {
        const u16x8 kf = ldfrag(kp, ct * 16 + lr, ks * 4 + lg);
        s1[ct] = mfma16(qh[ks], kf, s1[ct]);
        s2[ct] = mfma16(gh[ks], kf, s2[ct]);
      }
    }
#pragma unroll
    for (int r = 0; r < 4; ++r)
#pragma unroll
      for (int ct = 0; ct < 2; ++ct) {
        z1L[r] += exp2r(s1[ct][r] - C16L2);
        z2L[r] += exp2r(s2[ct][r] - C64L2);
      }
    __builtin_amdgcn_s_barrier();   // all waves done reading buf before overwrite
    __builtin_amdgcn_sched_barrier(0);
  }

  float rzr[4];
#pragma unroll
  for (int r = 0; r < 4; ++r) {
    float z1 = z1L[r], z2 = z2L[r];
#pragma unroll
    for (int msk = 1; msk < 16; msk <<= 1) {
      z1 += __shfl_xor(z1, msk);
      z2 += __shfl_xor(z2, msk);
    }
    rzr[r] = 1.f / (z1 * z2);
  }

  // pass-2 prologue loads fly while we finish u on the VALU
  stage_kf(0, 0);
  stage_vt(0, 0);

  // u = q' + g' (both already log2e-scaled), single fp16 (budgeted)
  u16x8 uh[2];
#pragma unroll
  for (int ks = 0; ks < 2; ++ks)
#pragma unroll
    for (int e = 0; e < 8; ++e)
      uh[ks][e] = f2h(h2f(qh[ks][e]) + gf[ks][e]);

  f32x4 o[4];
#pragma unroll
  for (int dt = 0; dt < 4; ++dt) { f32x4 z = {0.f, 0.f, 0.f, 0.f}; o[dt] = z; }

  float* wrow = attn + ((size_t)bh * S_ + q0) * S_;
  ushort* wsw = w_s[wv];

  // ---------------- pass 2: exact weights + PV, counted-vmcnt dbuf ----------
  for (int kt = 0; kt < 32; ++kt) {
    if (kt < 31) {
      stage_kf(kt + 1, (kt + 1) & 1);
      stage_vt(kt + 1, (kt + 1) & 1);
      if (kt == 0) asm volatile("s_waitcnt vmcnt(2)" ::: "memory");
      else         asm volatile("s_waitcnt vmcnt(4)" ::: "memory");
    } else {
      asm volatile("s_waitcnt vmcnt(2)" ::: "memory");  // [stage31:2][stores30:2]
    }
    __builtin_amdgcn_sched_barrier(0);
    __builtin_amdgcn_s_barrier();   // tile kt visible to all waves
    __builtin_amdgcn_sched_barrier(0);

    const int c = kt & 1;
    const ushort* kfp = kh2_s[c];
    const ushort* vtp = vt2_s[c];

    f32x4 s12[2];
#pragma unroll
    for (int ct = 0; ct < 2; ++ct) {
      f32x4 z = {0.f, 0.f, 0.f, 0.f};
      s12[ct] = z;
#pragma unroll
      for (int ks = 0; ks < 2; ++ks) {
        const u16x8 kf = ldfrag(kfp, ct * 16 + lr, ks * 4 + lg);
        s12[ct] = mfma16(uh[ks], kf, s12[ct]);
      }
    }
    // weights -> wave-private LDS (fp16, swizzled; keys 0..31 in chunks 0..3)
#pragma unroll
    for (int ct = 0; ct < 2; ++ct) {
#pragma unroll
      for (int r = 0; r < 4; ++r) {
        const int rowq = lg * 4 + r;
        const int key = ct * 16 + lr;
        const float wv2 = exp2r(s12[ct][r] - C80L2) * rzr[r];
        const int ch = (key >> 3) ^ (rowq & 7);
        wsw[rowq * 64 + ch * 8 + (key & 7)] = f2h(wv2);
      }
    }
    // PV (MFMA early; w from own-wave LDS, V from block tile)
    {
      const u16x8 af = ldfrag(wsw, lr, lg);
#pragma unroll
      for (int dt = 0; dt < 4; ++dt) {
        const u16x8 vf = ldfrag32(vtp, dt * 16 + lr, lg);
        o[dt] = mfma16(af, vf, o[dt]);
      }
    }
    // global fp32 weight store via own-wave LDS transpose (2x dwordx4/lane)
    {
      const int rowq = lane >> 2, cc = lane & 3;
      const int ch = cc ^ (rowq & 7);
      const uint4 wb = *reinterpret_cast<const uint4*>(&wsw[rowq * 64 + ch * 8]);
      const ushort* wp = reinterpret_cast<const ushort*>(&wb);
      float* dst = wrow + (size_t)rowq * S_ + kt * 32 + cc * 8;
      *reinterpret_cast<f4*>(dst) = make_float4(
          h2f(wp[0]), h2f(wp[1]), h2f(wp[2]), h2f(wp[3]));
      *reinterpret_cast<f4*>(dst + 4) = make_float4(
          h2f(wp[4]), h2f(wp[5]), h2f(wp[6]), h2f(wp[7]));
    }
    __builtin_amdgcn_s_barrier();   // all waves done reading buf before overwrite
    __builtin_amdgcn_sched_barrier(0);
  }

  // epilogue: ao[b][s][e] fp16
#pragma unroll
  for (int dt = 0; dt < 4; ++dt)
#pragma unroll
    for (int r = 0; r < 4; ++r)
      aoh[((size_t)b * S_ + q0 + lg * 4 + r) * E_ + h * 64 + dt * 16 + lr] =
          f2h(o[dt][r]);
}

extern "C" void kernel_launch(void* const* d_in, const int* in_sizes, int n_in,
                              void* d_out, int out_size, void* d_ws, size_t ws_size,
                              hipStream_t stream) {
  const float* x  = (const float*)d_in[0];
  const float* ge = (const float*)d_in[1];
  const float* Wq = (const float*)d_in[2];
  const float* bq = (const float*)d_in[3];
  const float* Wk = (const float*)d_in[4];
  const float* bk = (const float*)d_in[5];
  const float* Wv = (const float*)d_in[6];
  const float* bv = (const float*)d_in[7];
  const float* Wo = (const float*)d_in[8];
  const float* bo = (const float*)d_in[9];

  float* out  = (float*)d_out;
  float* attn = out + (size_t)B_ * S_ * E_;

  const size_t MSZ = 1024 * 1024;
  ushort* ws16 = (ushort*)d_ws;  // 48 MB used (ws ~1 GiB per fill counters)
  ushort* Wqf = ws16 + 0 * MSZ;
  ushort* Wkf = ws16 + 1 * MSZ;
  ushort* Wvf = ws16 + 2 * MSZ;
  ushort* Wof = ws16 + 3 * MSZ;
  ushort* xf  = ws16 + 4 * MSZ;   // fp16 x
  ushort* qh  = ws16 + 8 * MSZ;   // fp16 q (pre-scaled 0.125*log2e) [B,H,S,HD]
  ushort* kf  = ws16 + 12 * MSZ;  // fp16 k (single) [B,H,S,HD]
  ushort* vt  = ws16 + 16 * MSZ;  // fp16 v [B,H,HD,S]
  ushort* aoh = ws16 + 20 * MSZ;  // fp16 ao [B,S,E]

  dim3 blk(256);
  hipLaunchKernelGGL(prep_x, dim3(2048), blk, 0, stream, x, xf);
  hipLaunchKernelGGL(prep_w, dim3(16, 16, 4), blk, 0, stream, Wq, Wk, Wv, Wo, ws16);

  dim3 ggrid(E_ / 128, (B_ * S_) / 64);
  // Q: 1-term fp16, scale folds attention 0.125 AND log2e (exp2 softmax)
  hipLaunchKernelGGL((gemm_mfma<3>), ggrid, blk, 0, stream,
                     xf, Wqf, bq, 0.125f * LOG2E, qh, nullptr);
  // K: 1-term fp16
  hipLaunchKernelGGL((gemm_mfma<3>), ggrid, blk, 0, stream,
                     xf, Wkf, bk, 1.0f, kf, nullptr);
  // V: 1-term fp16, transposed output
  hipLaunchKernelGGL((gemm_mfma<2>), ggrid, blk, 0, stream,
                     xf, Wvf, bv, 1.0f, vt, nullptr);

  hipLaunchKernelGGL(attn_mfma, dim3(1024), blk, 0, stream,
                     qh, kf, vt, ge, attn, aoh);

  // O: 1-term fp16 -> fp32 out
  hipLaunchKernelGGL((gemm_mfma<0>), ggrid, blk, 0, stream,
                     aoh, Wof, bo, 1.0f, nullptr, out);
}